// Round 10
// baseline (113.710 us; speedup 1.0000x reference)
//
#include <hip/hip_runtime.h>
#include <hip/hip_bf16.h>

// Problem constants (fixed by setup_inputs)
#define B_N     64
#define C_ORIG  448
#define C_SEL   100
#define CPD     104      // packed channel count in D (13x16B rows, zeros at 100..103)
#define HW      3136     // 56*56
#define IMG     224

typedef short bf16x8 __attribute__((ext_vector_type(8)));
typedef float f32x4  __attribute__((ext_vector_type(4)));
typedef unsigned int u32x4 __attribute__((ext_vector_type(4)));

// packed f32 pair -> bf16x2 (compiles to v_cvt_pk_bf16_f32, RNE)
static __device__ __forceinline__ unsigned pkbf(float x, float y) {
    union { __hip_bfloat162 h; unsigned u; } c;
    c.h = __float22bfloat162_rn(float2{x, y});
    return c.u;
}
static __device__ __forceinline__ float bf2f(unsigned short h) {
    return __uint_as_float(((unsigned int)h) << 16);
}
// async global->LDS, 16B per lane (1KB per wave-instruction)
static __device__ __forceinline__ void gld16(const void* g, void* l) {
    __builtin_amdgcn_global_load_lds(
        (const __attribute__((address_space(1))) unsigned int*)g,
        (__attribute__((address_space(3))) unsigned int*)l, 16, 0, 0);
}
// async global->LDS, 4B per lane (256B per wave-instruction)
static __device__ __forceinline__ void gld4(const void* g, void* l) {
    __builtin_amdgcn_global_load_lds(
        (const __attribute__((address_space(1))) unsigned int*)g,
        (__attribute__((address_space(3))) unsigned int*)l, 4, 0, 0);
}

// ---------------------------------------------------------------------------
// Kernel A0: transpose mean[p][c] to meanT[c][p] so kA's mean loads coalesce.
// ---------------------------------------------------------------------------
__global__ __launch_bounds__(256) void kA0_meanT(const float* __restrict__ mean,
                                                 float* __restrict__ meanT)
{
    __shared__ float mt[64 * 100];
    const int tid = threadIdx.x;
    const int p0  = blockIdx.x * 64;
    const float4* src = reinterpret_cast<const float4*>(mean + (size_t)p0 * C_SEL);
#pragma unroll
    for (int q = 0; q < 7; ++q) {
        int idx4 = tid + q * 256;
        if (idx4 < 1600) {
            float4 v = src[idx4];
            *reinterpret_cast<float4*>(&mt[idx4 * 4]) = v;
        }
    }
    __syncthreads();
#pragma unroll
    for (int q = 0; q < 7; ++q) {
        int u = tid + q * 256;
        if (u < 1600) {
            int c = u >> 4, s = u & 15;
            float4 v;
            v.x = mt[(s * 4 + 0) * 100 + c];
            v.y = mt[(s * 4 + 1) * 100 + c];
            v.z = mt[(s * 4 + 2) * 100 + c];
            v.w = mt[(s * 4 + 3) * 100 + c];
            *reinterpret_cast<float4*>(meanT + (size_t)c * HW + p0 + s * 4) = v;
        }
    }
}

// ---------------------------------------------------------------------------
// Kernel A: gather selected channels via global_load_lds (feats/meanT halves
// staged as f32 [c][64p] LDS tiles; 256B per gld4 instruction, no data-VGPRs),
// subtract+bf16-cast from conflict-free LDS column reads, swizzle-write the
// 16KB Dt transpose tile, store D[p][b][c] (c packed to 104).
// LDS 42.6KB -> 3 blocks/CU; per-wave VMEM instrs ~54 (vs 213 scalar-load kA).
// ---------------------------------------------------------------------------
__global__ __launch_bounds__(256) void kA_gather(const float* __restrict__ feats,
                                                 const float* __restrict__ meanT,
                                                 const int* __restrict__ sel,
                                                 unsigned short* __restrict__ D)
{
    __shared__ float ft[52 * 64];             // 13.3 KB (half-tile, feats)
    __shared__ float mt[52 * 64];             // 13.3 KB (half-tile, meanT)
    __shared__ unsigned short Dt[64 * 128];   // 16 KB transpose tile
    char* DtB = reinterpret_cast<char*>(Dt);
    const int tid = threadIdx.x;
    const int p0  = blockIdx.x * 64;
    const int b   = blockIdx.y;
    const int w    = tid >> 6;
    const int lane = tid & 63;

    // zero pad unit 25 (c 100..103) for all 64 rows — disjoint bytes
    if (tid < 64) {
        int pr = tid;
        *reinterpret_cast<uint2*>(DtB + pr * 256 + (200u ^ ((pr & 31) << 3)))
            = make_uint2(0u, 0u);
    }

    const float* fbase = feats + (size_t)b * (C_ORIG * HW) + p0 + lane;
    const float* mbase = meanT + p0 + lane;
    const unsigned swz = (unsigned)(lane & 31) << 3;
    char* rowB = DtB + lane * 256;

#pragma unroll
    for (int h = 0; h < 2; ++h) {
        const int cbase = h ? 48 : 0;
        const int ccnt  = h ? 52 : 48;        // both divisible by 4
        // stage half: wave w issues channels c = w, w+4, ... (async, deep queue)
        for (int c = w; c < ccnt; c += 4) {
            int gc = cbase + c;
            gld4(fbase + (size_t)sel[gc] * HW, &ft[c * 64]);
            gld4(mbase + (size_t)gc * HW,      &mt[c * 64]);
        }
        __syncthreads();   // drains vmcnt: half-tile landed

        // compute quads: wave w handles q = w, w+4, ...; lane = p
        for (int q = w; q < (ccnt >> 2); q += 4) {
            int c = q * 4;
            float v0 = ft[(c + 0) * 64 + lane] - mt[(c + 0) * 64 + lane];
            float v1 = ft[(c + 1) * 64 + lane] - mt[(c + 1) * 64 + lane];
            float v2 = ft[(c + 2) * 64 + lane] - mt[(c + 2) * 64 + lane];
            float v3 = ft[(c + 3) * 64 + lane] - mt[(c + 3) * 64 + lane];
            uint2 pk = make_uint2(pkbf(v0, v1), pkbf(v2, v3));
            int gc0 = cbase + c;
            *reinterpret_cast<uint2*>(rowB + (((unsigned)(2 * gc0)) ^ swz)) = pk;
        }
        __syncthreads();   // protect ft/mt before next stage / Dt before phase 3
    }

    // un-swizzle + write D rows (13 x 16B slots per p, coalesced)
    char* DpB = reinterpret_cast<char*>(D) + ((size_t)p0 * B_N + b) * (CPD * 2);
#pragma unroll
    for (int q = 0; q < 4; ++q) {
        int unit = tid + q * 256;       // 0..831
        if (unit < 832) {
            int pr = unit / 13;
            int s  = unit % 13;
            unsigned off = ((unsigned)(16 * s)) ^ ((((unsigned)pr & 31u) << 3) & 0xF0u);
            u32x4 v = *reinterpret_cast<const u32x4*>(DtB + pr * 256 + off);
            u32x4 r = (pr & 1) ? __builtin_shufflevector(v, v, 2, 3, 0, 1) : v;
            *reinterpret_cast<u32x4*>(DpB + (size_t)pr * (B_N * CPD * 2) + s * 16) = r;
        }
    }
}

// ---------------------------------------------------------------------------
// Kernel B: per-pixel Mahalanobis via MFMA. icov[p] staged RAW f32 into LDS
// via global_load_lds (40 chunks x 1KB; no data-VGPRs -> deep in-flight
// queue, BW-saturating). bf16 conversion happens on fragment read (cvt_pk).
// 40KB LDS linear [i][j] (400B rows) -> 4 blocks/CU. One barrier.
// ---------------------------------------------------------------------------
__global__ __launch_bounds__(256, 4) void kB_maha(const float* __restrict__ icov,
                                                  const unsigned short* __restrict__ D,
                                                  float* __restrict__ dist)
{
    __shared__ float Mf[10000];   // 40000 B, linear [i][j], row stride 400B
    const int tid  = threadIdx.x;
    const int p    = blockIdx.x;
    const int w    = tid >> 6;
    const int lane = tid & 63;
    const int lrow = lane & 15;
    const int g    = lane >> 4;
    const int bcol = w * 16 + lrow;
    const unsigned short* Drow = D + ((size_t)p * B_N + bcol) * CPD;

    // stage icov[p] -> LDS raw f32: 40 x 1KB chunks, wave w owns chunks w*10..w*10+9
    {
        const char* srcB = reinterpret_cast<const char*>(icov + (size_t)p * (C_SEL * C_SEL));
        char* ldsB = reinterpret_cast<char*>(Mf);
#pragma unroll
        for (int q = 0; q < 10; ++q) {
            int chunk = w * 10 + q;
            if (chunk < 39) {
                gld16(srcB + chunk * 1024 + lane * 16, ldsB + chunk * 1024);
            } else if (lane < 4) {   // chunk 39: only 64B remain (row 99 cols 84..99)
                gld16(srcB + 39 * 1024 + lane * 16, ldsB + 39 * 1024);
            }
        }
    }

    // hoist B-fragment reads (independent of LDS; fly under the icov stream)
    bf16x8 bfr[4];
#pragma unroll
    for (int ks = 0; ks < 4; ++ks)
        bfr[ks] = *reinterpret_cast<const bf16x8*>(Drow + ks * 32 + g * 8);

    __syncthreads();   // waits vmcnt(0): all gload_lds data landed

    // epilogue D values (L1-hot)
    ushort4 dvec[7];
#pragma unroll
    for (int it = 0; it < 7; ++it)
        dvec[it] = *reinterpret_cast<const ushort4*>(Drow + it * 16 + g * 4);

    f32x4 acc[7];
#pragma unroll
    for (int it = 0; it < 7; ++it) acc[it] = (f32x4){0.f, 0.f, 0.f, 0.f};

#pragma unroll
    for (int ks = 0; ks < 4; ++ks) {
#pragma unroll
        for (int it = 0; it < 7; ++it) {
            u32x4 u = {0u, 0u, 0u, 0u};
            if (it < 6 || lrow < 4) {            // rows >=100 -> zero (discarded outputs)
                int i = it * 16 + lrow;
                const float* rp = &Mf[i * 100 + ks * 32 + g * 8];
                if (ks < 3) {                    // cols fully in range
                    f32x4 a = *reinterpret_cast<const f32x4*>(rp);
                    f32x4 bv = *reinterpret_cast<const f32x4*>(rp + 4);
                    u[0] = pkbf(a[0], a[1]);  u[1] = pkbf(a[2], a[3]);
                    u[2] = pkbf(bv[0], bv[1]); u[3] = pkbf(bv[2], bv[3]);
                } else if (g == 0) {             // ks=3: cols 96..99 valid, rest zero
                    f32x4 a = *reinterpret_cast<const f32x4*>(rp);
                    u[0] = pkbf(a[0], a[1]);  u[1] = pkbf(a[2], a[3]);
                }                                 // ks=3, g>0: all-zero fragment
            }
            acc[it] = __builtin_amdgcn_mfma_f32_16x16x32_bf16(
                __builtin_bit_cast(bf16x8, u), bfr[ks], acc[it], 0, 0, 0);
        }
    }

    // epilogue: dist[b] = sum_i D[b,i] * Z[i,b]; C/D layout col=lane&15, row=g*4+r
    float partial = 0.f;
#pragma unroll
    for (int it = 0; it < 7; ++it) {
#pragma unroll
        for (int r = 0; r < 4; ++r) {
            int i = it * 16 + g * 4 + r;
            if (i < C_SEL) {
                unsigned short dh = (r == 0) ? dvec[it].x : (r == 1) ? dvec[it].y
                                   : (r == 2) ? dvec[it].z : dvec[it].w;
                partial += acc[it][r] * bf2f(dh);
            }
        }
    }
    partial += __shfl_xor(partial, 16);
    partial += __shfl_xor(partial, 32);
    if (g == 0) dist[p * B_N + bcol] = partial;   // dist[p][b], contiguous 256B/block
}

// ---------------------------------------------------------------------------
// Kernel C: bilinear 56 -> 224, LDS row staging, split into b-halves for TLP.
// grid (224, 2).
// ---------------------------------------------------------------------------
__global__ __launch_bounds__(256) void kC_resize(const float* __restrict__ dist,
                                                 float* __restrict__ out)
{
    __shared__ float L[2 * 56 * 34];   // 14.9 KB
    const int tid  = threadIdx.x;
    const int y    = blockIdx.x;
    const int half = blockIdx.y;

    float sy = y * 0.25f - 0.375f;
    float fy0 = floorf(sy);
    float fy = sy - fy0;
    int y0 = max((int)fy0, 0);
    int y1 = min((int)fy0 + 1, 55);
    int rsrc[2] = {y0, y1};

#pragma unroll
    for (int r = 0; r < 2; ++r) {
        const float4* s4 = reinterpret_cast<const float4*>(dist + (size_t)rsrc[r] * 56 * B_N);
#pragma unroll
        for (int j = 0; j < 2; ++j) {
            int idx = tid + j * 256;
            if (idx < 448) {                 // 448 float4 = 56*32 floats
                int m = idx >> 3;            // 8 float4 per m-row half
                int k = idx & 7;
                float4 v = s4[m * 16 + half * 8 + k];
                float* d = &L[r * 56 * 34 + m * 34 + k * 4];
                d[0] = v.x; d[1] = v.y; d[2] = v.z; d[3] = v.w;
            }
        }
    }
    __syncthreads();

    // unit = b*56 + m (b local 0..31): compute out[half*32+b][y][4m..4m+3]
#pragma unroll
    for (int j = 0; j < 7; ++j) {
        int unit = tid + j * 256;            // 0..1791 = 32*56
        int b = unit / 56;
        int m = unit % 56;
        int xm1 = max(m - 1, 0);
        int xp1 = min(m + 1, 55);

        const float* L0 = &L[0 * 56 * 34];
        const float* L1 = &L[1 * 56 * 34];
        float a0 = L0[xm1 * 34 + b], b0 = L0[m * 34 + b], c0 = L0[xp1 * 34 + b];
        float a1 = L1[xm1 * 34 + b], b1 = L1[m * 34 + b], c1 = L1[xp1 * 34 + b];

        float A  = a0 + fy * (a1 - a0);
        float Bv = b0 + fy * (b1 - b0);
        float Cv = c0 + fy * (c1 - c0);

        float4 o;
        o.x = A  + 0.625f * (Bv - A);    // x=4m:   x0=m-1, fx=0.625
        o.y = A  + 0.875f * (Bv - A);    // x=4m+1: fx=0.875
        o.z = Bv + 0.125f * (Cv - Bv);   // x=4m+2: x0=m,   fx=0.125
        o.w = Bv + 0.375f * (Cv - Bv);   // x=4m+3: fx=0.375
        *reinterpret_cast<float4*>(out + ((size_t)(half * 32 + b) * IMG + y) * IMG + 4 * m) = o;
    }
}

extern "C" void kernel_launch(void* const* d_in, const int* in_sizes, int n_in,
                              void* d_out, int out_size, void* d_ws, size_t ws_size,
                              hipStream_t stream)
{
    const float* feats = (const float*)d_in[0];
    const float* mean  = (const float*)d_in[1];
    const float* icov  = (const float*)d_in[2];
    const int*   sel   = (const int*)d_in[3];
    float* out = (float*)d_out;

    char* ws = (char*)d_ws;
    unsigned short* Dws = (unsigned short*)ws;                    // 41.7 MB
    size_t off = (size_t)HW * B_N * CPD * 2;
    float* distws = (float*)(ws + off);                           // +803 KB
    off += (size_t)HW * B_N * 4;
    float* meanT = (float*)(ws + off);                            // +1.25 MB

    kA0_meanT<<<49, 256, 0, stream>>>(mean, meanT);
    dim3 gA(49, B_N);
    kA_gather<<<gA, 256, 0, stream>>>(feats, meanT, sel, Dws);
    kB_maha<<<HW, 256, 0, stream>>>(icov, Dws, distws);
    dim3 gC(IMG, 2);
    kC_resize<<<gC, 256, 0, stream>>>(distws, out);
}

// Round 11
// 72.149 us; speedup vs baseline: 1.5761x; 1.5761x over previous
//
#include <hip/hip_runtime.h>
#include <hip/hip_bf16.h>

// Problem constants (fixed by setup_inputs)
#define B_N     64
#define C_ORIG  448
#define C_SEL   100
#define CPD     104      // packed channel count in D (13x16B rows, zeros at 100..103)
#define HW      3136     // 56*56
#define IMG     224

typedef short bf16x8 __attribute__((ext_vector_type(8)));
typedef float f32x4  __attribute__((ext_vector_type(4)));
typedef unsigned int u32x4 __attribute__((ext_vector_type(4)));

// packed f32 pair -> bf16x2 (compiles to v_cvt_pk_bf16_f32, RNE)
static __device__ __forceinline__ unsigned pkbf(float x, float y) {
    union { __hip_bfloat162 h; unsigned u; } c;
    c.h = __float22bfloat162_rn(float2{x, y});
    return c.u;
}
static __device__ __forceinline__ float bf2f(unsigned short h) {
    return __uint_as_float(((unsigned int)h) << 16);
}
// async global->LDS, 16B per lane (1KB per wave-instruction)
static __device__ __forceinline__ void gld16(const void* g, void* l) {
    __builtin_amdgcn_global_load_lds(
        (const __attribute__((address_space(1))) unsigned int*)g,
        (__attribute__((address_space(3))) unsigned int*)l, 16, 0, 0);
}

// ---------------------------------------------------------------------------
// Kernel A0: transpose mean[p][c] to meanT[c][p] so kA's mean loads coalesce.
// ---------------------------------------------------------------------------
__global__ __launch_bounds__(256) void kA0_meanT(const float* __restrict__ mean,
                                                 float* __restrict__ meanT)
{
    __shared__ float mt[64 * 100];
    const int tid = threadIdx.x;
    const int p0  = blockIdx.x * 64;
    const float4* src = reinterpret_cast<const float4*>(mean + (size_t)p0 * C_SEL);
#pragma unroll
    for (int q = 0; q < 7; ++q) {
        int idx4 = tid + q * 256;
        if (idx4 < 1600) {
            float4 v = src[idx4];
            *reinterpret_cast<float4*>(&mt[idx4 * 4]) = v;
        }
    }
    __syncthreads();
#pragma unroll
    for (int q = 0; q < 7; ++q) {
        int u = tid + q * 256;
        if (u < 1600) {
            int c = u >> 4, s = u & 15;
            float4 v;
            v.x = mt[(s * 4 + 0) * 100 + c];
            v.y = mt[(s * 4 + 1) * 100 + c];
            v.z = mt[(s * 4 + 2) * 100 + c];
            v.w = mt[(s * 4 + 3) * 100 + c];
            *reinterpret_cast<float4*>(meanT + (size_t)c * HW + p0 + s * 4) = v;
        }
    }
}

// ---------------------------------------------------------------------------
// Kernel A: gather selected channels, subtract meanT (coalesced), bf16-cast,
// transpose to D[p][b][c] (c packed to 104, zeros at 100..103).
// LDS: 16KB (256B row stride for XOR swizzle); 8B unit u of row p at byte
// (8u)^((p&31)<<3). One barrier. 8 blocks/CU.
// ---------------------------------------------------------------------------
__global__ __launch_bounds__(256) void kA_gather(const float* __restrict__ feats,
                                                 const float* __restrict__ meanT,
                                                 const int* __restrict__ sel,
                                                 unsigned short* __restrict__ D)
{
    __shared__ unsigned short Dt[64 * 128];   // 16 KB
    char* DtB = reinterpret_cast<char*>(Dt);
    const int tid = threadIdx.x;
    const int p0  = blockIdx.x * 64;
    const int b   = blockIdx.y;

    // zero pad unit 25 (c 100..103) for all 64 rows — disjoint bytes
    if (tid < 64) {
        int pr = tid;
        *reinterpret_cast<uint2*>(DtB + pr * 256 + (200 ^ ((pr & 31) << 3)))
            = make_uint2(0u, 0u);
    }

    const int w    = tid >> 6;
    const int lane = tid & 63;
    const float* fb = feats + (size_t)b * (C_ORIG * HW) + p0 + lane;
    const float* mb = meanT + p0 + lane;
    const unsigned swz = (unsigned)(lane & 31) << 3;
    char* rowB = DtB + lane * 256;

    auto quad = [&](int c0) {
        int ch0 = sel[c0], ch1 = sel[c0 + 1], ch2 = sel[c0 + 2], ch3 = sel[c0 + 3];
        float v0 = fb[(size_t)ch0 * HW] - mb[(size_t)(c0 + 0) * HW];
        float v1 = fb[(size_t)ch1 * HW] - mb[(size_t)(c0 + 1) * HW];
        float v2 = fb[(size_t)ch2 * HW] - mb[(size_t)(c0 + 2) * HW];
        float v3 = fb[(size_t)ch3 * HW] - mb[(size_t)(c0 + 3) * HW];
        uint2 pk = make_uint2(pkbf(v0, v1), pkbf(v2, v3));
        *reinterpret_cast<uint2*>(rowB + (((unsigned)(2 * c0)) ^ swz)) = pk;
    };

    if (w < 3) {
#pragma unroll
        for (int q = 0; q < 6; ++q) quad(w * 24 + q * 4);   // waves 0-2: 24 ch each
    } else {
#pragma unroll
        for (int q = 0; q < 7; ++q) quad(72 + q * 4);       // wave 3: 28 ch
    }
    __syncthreads();

    // un-swizzle + write D rows (13 x 16B slots per p, coalesced)
    char* DpB = reinterpret_cast<char*>(D) + ((size_t)p0 * B_N + b) * (CPD * 2);
#pragma unroll
    for (int q = 0; q < 4; ++q) {
        int unit = tid + q * 256;       // 0..831
        if (unit < 832) {
            int pr = unit / 13;
            int s  = unit % 13;
            unsigned off = ((unsigned)(16 * s)) ^ ((((unsigned)pr & 31u) << 3) & 0xF0u);
            u32x4 v = *reinterpret_cast<const u32x4*>(DtB + pr * 256 + off);
            u32x4 r = (pr & 1) ? __builtin_shufflevector(v, v, 2, 3, 0, 1) : v;
            *reinterpret_cast<u32x4*>(DpB + (size_t)pr * (B_N * CPD * 2) + s * 16) = r;
        }
    }
}

// ---------------------------------------------------------------------------
// Kernel B: per-pixel Mahalanobis via MFMA. icov[p] staged RAW f32 into LDS
// via global_load_lds (40 chunks x 1KB; no data-VGPRs -> deep in-flight
// queue, BW-saturating). bf16 conversion happens on fragment read (cvt_pk).
// 40KB LDS linear [i][j] (400B rows) -> 4 blocks/CU. One barrier.
// ---------------------------------------------------------------------------
__global__ __launch_bounds__(256, 4) void kB_maha(const float* __restrict__ icov,
                                                  const unsigned short* __restrict__ D,
                                                  float* __restrict__ dist)
{
    __shared__ float Mf[10000];   // 40000 B, linear [i][j], row stride 400B
    const int tid  = threadIdx.x;
    const int p    = blockIdx.x;
    const int w    = tid >> 6;
    const int lane = tid & 63;
    const int lrow = lane & 15;
    const int g    = lane >> 4;
    const int bcol = w * 16 + lrow;
    const unsigned short* Drow = D + ((size_t)p * B_N + bcol) * CPD;

    // stage icov[p] -> LDS raw f32: 40 x 1KB chunks, wave w owns chunks w*10..w*10+9
    {
        const char* srcB = reinterpret_cast<const char*>(icov + (size_t)p * (C_SEL * C_SEL));
        char* ldsB = reinterpret_cast<char*>(Mf);
#pragma unroll
        for (int q = 0; q < 10; ++q) {
            int chunk = w * 10 + q;
            if (chunk < 39) {
                gld16(srcB + chunk * 1024 + lane * 16, ldsB + chunk * 1024);
            } else if (lane < 4) {   // chunk 39: only 64B remain (row 99 cols 84..99)
                gld16(srcB + 39 * 1024 + lane * 16, ldsB + 39 * 1024);
            }
        }
    }

    // hoist B-fragment reads (independent of LDS; fly under the icov stream)
    bf16x8 bfr[4];
#pragma unroll
    for (int ks = 0; ks < 4; ++ks)
        bfr[ks] = *reinterpret_cast<const bf16x8*>(Drow + ks * 32 + g * 8);

    __syncthreads();   // waits vmcnt(0): all gload_lds data landed

    // epilogue D values (L1-hot)
    ushort4 dvec[7];
#pragma unroll
    for (int it = 0; it < 7; ++it)
        dvec[it] = *reinterpret_cast<const ushort4*>(Drow + it * 16 + g * 4);

    f32x4 acc[7];
#pragma unroll
    for (int it = 0; it < 7; ++it) acc[it] = (f32x4){0.f, 0.f, 0.f, 0.f};

#pragma unroll
    for (int ks = 0; ks < 4; ++ks) {
#pragma unroll
        for (int it = 0; it < 7; ++it) {
            u32x4 u = {0u, 0u, 0u, 0u};
            if (it < 6 || lrow < 4) {            // rows >=100 -> zero (discarded outputs)
                int i = it * 16 + lrow;
                const float* rp = &Mf[i * 100 + ks * 32 + g * 8];
                if (ks < 3) {                    // cols fully in range
                    f32x4 a = *reinterpret_cast<const f32x4*>(rp);
                    f32x4 bv = *reinterpret_cast<const f32x4*>(rp + 4);
                    u[0] = pkbf(a[0], a[1]);  u[1] = pkbf(a[2], a[3]);
                    u[2] = pkbf(bv[0], bv[1]); u[3] = pkbf(bv[2], bv[3]);
                } else if (g == 0) {             // ks=3: cols 96..99 valid, rest zero
                    f32x4 a = *reinterpret_cast<const f32x4*>(rp);
                    u[0] = pkbf(a[0], a[1]);  u[1] = pkbf(a[2], a[3]);
                }                                 // ks=3, g>0: all-zero fragment
            }
            acc[it] = __builtin_amdgcn_mfma_f32_16x16x32_bf16(
                __builtin_bit_cast(bf16x8, u), bfr[ks], acc[it], 0, 0, 0);
        }
    }

    // epilogue: dist[b] = sum_i D[b,i] * Z[i,b]; C/D layout col=lane&15, row=g*4+r
    float partial = 0.f;
#pragma unroll
    for (int it = 0; it < 7; ++it) {
#pragma unroll
        for (int r = 0; r < 4; ++r) {
            int i = it * 16 + g * 4 + r;
            if (i < C_SEL) {
                unsigned short dh = (r == 0) ? dvec[it].x : (r == 1) ? dvec[it].y
                                   : (r == 2) ? dvec[it].z : dvec[it].w;
                partial += acc[it][r] * bf2f(dh);
            }
        }
    }
    partial += __shfl_xor(partial, 16);
    partial += __shfl_xor(partial, 32);
    if (g == 0) dist[p * B_N + bcol] = partial;   // dist[p][b], contiguous 256B/block
}

// ---------------------------------------------------------------------------
// Kernel C: bilinear 56 -> 224, LDS row staging, split into b-halves for TLP.
// grid (224, 2).
// ---------------------------------------------------------------------------
__global__ __launch_bounds__(256) void kC_resize(const float* __restrict__ dist,
                                                 float* __restrict__ out)
{
    __shared__ float L[2 * 56 * 34];   // 14.9 KB
    const int tid  = threadIdx.x;
    const int y    = blockIdx.x;
    const int half = blockIdx.y;

    float sy = y * 0.25f - 0.375f;
    float fy0 = floorf(sy);
    float fy = sy - fy0;
    int y0 = max((int)fy0, 0);
    int y1 = min((int)fy0 + 1, 55);
    int rsrc[2] = {y0, y1};

#pragma unroll
    for (int r = 0; r < 2; ++r) {
        const float4* s4 = reinterpret_cast<const float4*>(dist + (size_t)rsrc[r] * 56 * B_N);
#pragma unroll
        for (int j = 0; j < 2; ++j) {
            int idx = tid + j * 256;
            if (idx < 448) {                 // 448 float4 = 56*32 floats
                int m = idx >> 3;            // 8 float4 per m-row half
                int k = idx & 7;
                float4 v = s4[m * 16 + half * 8 + k];
                float* d = &L[r * 56 * 34 + m * 34 + k * 4];
                d[0] = v.x; d[1] = v.y; d[2] = v.z; d[3] = v.w;
            }
        }
    }
    __syncthreads();

    // unit = b*56 + m (b local 0..31): compute out[half*32+b][y][4m..4m+3]
#pragma unroll
    for (int j = 0; j < 7; ++j) {
        int unit = tid + j * 256;            // 0..1791 = 32*56
        int b = unit / 56;
        int m = unit % 56;
        int xm1 = max(m - 1, 0);
        int xp1 = min(m + 1, 55);

        const float* L0 = &L[0 * 56 * 34];
        const float* L1 = &L[1 * 56 * 34];
        float a0 = L0[xm1 * 34 + b], b0 = L0[m * 34 + b], c0 = L0[xp1 * 34 + b];
        float a1 = L1[xm1 * 34 + b], b1 = L1[m * 34 + b], c1 = L1[xp1 * 34 + b];

        float A  = a0 + fy * (a1 - a0);
        float Bv = b0 + fy * (b1 - b0);
        float Cv = c0 + fy * (c1 - c0);

        float4 o;
        o.x = A  + 0.625f * (Bv - A);    // x=4m:   x0=m-1, fx=0.625
        o.y = A  + 0.875f * (Bv - A);    // x=4m+1: fx=0.875
        o.z = Bv + 0.125f * (Cv - Bv);   // x=4m+2: x0=m,   fx=0.125
        o.w = Bv + 0.375f * (Cv - Bv);   // x=4m+3: fx=0.375
        *reinterpret_cast<float4*>(out + ((size_t)(half * 32 + b) * IMG + y) * IMG + 4 * m) = o;
    }
}

extern "C" void kernel_launch(void* const* d_in, const int* in_sizes, int n_in,
                              void* d_out, int out_size, void* d_ws, size_t ws_size,
                              hipStream_t stream)
{
    const float* feats = (const float*)d_in[0];
    const float* mean  = (const float*)d_in[1];
    const float* icov  = (const float*)d_in[2];
    const int*   sel   = (const int*)d_in[3];
    float* out = (float*)d_out;

    char* ws = (char*)d_ws;
    unsigned short* Dws = (unsigned short*)ws;                    // 41.7 MB
    size_t off = (size_t)HW * B_N * CPD * 2;
    float* distws = (float*)(ws + off);                           // +803 KB
    off += (size_t)HW * B_N * 4;
    float* meanT = (float*)(ws + off);                            // +1.25 MB

    kA0_meanT<<<49, 256, 0, stream>>>(mean, meanT);
    dim3 gA(49, B_N);
    kA_gather<<<gA, 256, 0, stream>>>(feats, meanT, sel, Dws);
    kB_maha<<<HW, 256, 0, stream>>>(icov, Dws, distws);
    dim3 gC(IMG, 2);
    kC_resize<<<gC, 256, 0, stream>>>(distws, out);
}